// Round 1
// baseline (544.088 us; speedup 1.0000x reference)
//
#include <hip/hip_runtime.h>
#include <math.h>

// Problem constants
#define XD 128
#define YD 128
#define ZD 8
#define ED 64
#define KD 3
#define NITER 3
#define FHD 96
#define FWD 320
// coord normalization uses the ORIGINAL image size (384 x 1280)
#define HALF_W 640.0f
#define HALF_H 192.0f

__device__ __forceinline__ float wsum64(float v) {
    v += __shfl_xor(v, 1, 64);
    v += __shfl_xor(v, 2, 64);
    v += __shfl_xor(v, 4, 64);
    v += __shfl_xor(v, 8, 64);
    v += __shfl_xor(v, 16, 64);
    v += __shfl_xor(v, 32, 64);
    return v;
}

__device__ __forceinline__ float bcast_lane(float v, int lane) {
    return __int_as_float(__builtin_amdgcn_readlane(__float_as_int(v), lane));
}

// Transpose img_feat (1,E,FH,FW) -> (FH*FW, E) HWC for coalesced channel loads
__global__ void k_img_hwc(const float* __restrict__ img, float* __restrict__ out) {
    int idx = blockIdx.x * blockDim.x + threadIdx.x;  // e fastest
    if (idx >= FHD * FWD * ED) return;
    int e = idx & (ED - 1);
    int hw = idx >> 6;
    out[idx] = img[e * (FHD * FWD) + hw];
}

__global__ __launch_bounds__(256) void k_main(
    const float* __restrict__ Tv,     // (3,4)
    const float* __restrict__ intr,   // (3,3)
    const float* __restrict__ imgHWC, // (FH*FW, E)
    const float* __restrict__ bev_in, // (X,Y,Z,E)
    const float* __restrict__ W_off,  // (I,E,6)
    const float* __restrict__ b_off,  // (I,6)
    const float* __restrict__ s_off,  // (I,)
    const float* __restrict__ W_w,    // (I,E,3)
    const float* __restrict__ b_w,    // (I,3)
    const float* __restrict__ W_l,    // (I,E,E)
    const float* __restrict__ b_l,    // (I,E)
    const float* __restrict__ ln_g,   // (I,E)
    const float* __restrict__ ln_b,   // (I,E)
    float* __restrict__ tmp)          // (Y*X, E)  p = y*X + x
{
    const int lane = threadIdx.x & 63;
    const int wid = blockIdx.x * (blockDim.x >> 6) + (threadIdx.x >> 6);
    const int x = wid & (XD - 1);
    const int y = wid >> 7;

    // T = intr @ Tv (3x4)
    float T[12];
#pragma unroll
    for (int r = 0; r < 3; ++r)
#pragma unroll
        for (int c = 0; c < 4; ++c)
            T[r * 4 + c] = intr[r * 3 + 0] * Tv[0 * 4 + c] +
                           intr[r * 3 + 1] * Tv[1 * 4 + c] +
                           intr[r * 3 + 2] * Tv[2 * 4 + c];

    const float gx = x * 0.8f;
    const float gy = 51.2f - y * 0.8f;

    float cx[ZD], cy[ZD];
#pragma unroll
    for (int z = 0; z < ZD; ++z) {
        float gz = z * 0.5f - 2.5f;
        float p0 = T[0] * gx + T[1] * gy + T[2] * gz + T[3];
        float p1 = T[4] * gx + T[5] * gy + T[6] * gz + T[7];
        float p2 = T[8] * gx + T[9] * gy + T[10] * gz + T[11];
        float u = p0 / p2;
        float v = p1 / p2;
        cx[z] = u / HALF_W - 1.0f;
        cy[z] = v / HALF_H - 1.0f;
    }

    float bev[ZD];
    const int pbase = (((x << 7) | y) << 9);  // ((x*128+y)*8)*64
#pragma unroll
    for (int z = 0; z < ZD; ++z) bev[z] = bev_in[pbase + z * ED + lane];

    for (int i = 0; i < NITER; ++i) {
        // per-lane (channel) weights
        float wo[6], wwt[3];
#pragma unroll
        for (int j = 0; j < 6; ++j) wo[j] = W_off[(i * ED + lane) * 6 + j];
#pragma unroll
        for (int j = 0; j < 3; ++j) wwt[j] = W_w[(i * ED + lane) * 3 + j];
        float bo[6], bwv[3];
#pragma unroll
        for (int j = 0; j < 6; ++j) bo[j] = b_off[i * 6 + j];
#pragma unroll
        for (int j = 0; j < 3; ++j) bwv[j] = b_w[i * 3 + j];
        const float so = s_off[i];
        float wl[ED];  // W_l column for this lane's output channel
#pragma unroll
        for (int ep = 0; ep < ED; ++ep) wl[ep] = W_l[(i * ED + ep) * ED + lane];
        const float blv = b_l[i * ED + lane];
        const float gv = ln_g[i * ED + lane];
        const float btv = ln_b[i * ED + lane];

#pragma unroll
        for (int z = 0; z < ZD; ++z) {
            float b = bev[z];
            // 9 dot products over E via butterfly reductions
            float s0 = wsum64(b * wo[0]);
            float s1 = wsum64(b * wo[1]);
            float s2 = wsum64(b * wo[2]);
            float s3 = wsum64(b * wo[3]);
            float s4 = wsum64(b * wo[4]);
            float s5 = wsum64(b * wo[5]);
            float t0 = wsum64(b * wwt[0]);
            float t1 = wsum64(b * wwt[1]);
            float t2 = wsum64(b * wwt[2]);

            float offv[6];
            offv[0] = (s0 + bo[0]) * so;
            offv[1] = (s1 + bo[1]) * so;
            offv[2] = (s2 + bo[2]) * so;
            offv[3] = (s3 + bo[3]) * so;
            offv[4] = (s4 + bo[4]) * so;
            offv[5] = (s5 + bo[5]) * so;

            float l0 = t0 + bwv[0], l1 = t1 + bwv[1], l2 = t2 + bwv[2];
            float m = fmaxf(fmaxf(l0, l1), l2);
            float e0 = __expf(l0 - m), e1 = __expf(l1 - m), e2 = __expf(l2 - m);
            float inv = 1.0f / (e0 + e1 + e2);
            float wk[3] = {e0 * inv, e1 * inv, e2 * inv};

            float feat = 0.0f;
#pragma unroll
            for (int k = 0; k < KD; ++k) {
                float gxx = cx[z] + offv[2 * k + 0];
                float gyy = cy[z] + offv[2 * k + 1];
                float px = ((gxx + 1.0f) * (float)FWD - 1.0f) * 0.5f;
                float py = ((gyy + 1.0f) * (float)FHD - 1.0f) * 0.5f;
                float x0f = floorf(px), y0f = floorf(py);
                float fx = px - x0f, fy = py - y0f;
                int ix0 = (int)x0f, iy0 = (int)y0f;
                int ix1 = ix0 + 1, iy1 = iy0 + 1;
                float mx0 = (ix0 >= 0 && ix0 < FWD) ? 1.0f : 0.0f;
                float mx1 = (ix1 >= 0 && ix1 < FWD) ? 1.0f : 0.0f;
                float my0 = (iy0 >= 0 && iy0 < FHD) ? 1.0f : 0.0f;
                float my1 = (iy1 >= 0 && iy1 < FHD) ? 1.0f : 0.0f;
                int cx0 = min(max(ix0, 0), FWD - 1);
                int cx1 = min(max(ix1, 0), FWD - 1);
                int cy0 = min(max(iy0, 0), FHD - 1);
                int cy1 = min(max(iy1, 0), FHD - 1);
                float v00 = imgHWC[(cy0 * FWD + cx0) * ED + lane] * (mx0 * my0);
                float v10 = imgHWC[(cy0 * FWD + cx1) * ED + lane] * (mx1 * my0);
                float v01 = imgHWC[(cy1 * FWD + cx0) * ED + lane] * (mx0 * my1);
                float v11 = imgHWC[(cy1 * FWD + cx1) * ED + lane] * (mx1 * my1);
                float wx1 = fx, wx0 = 1.0f - fx;
                float wy1 = fy, wy0 = 1.0f - fy;
                float bil = v00 * (wx0 * wy0) + v10 * (wx1 * wy0) +
                            v01 * (wx0 * wy1) + v11 * (wx1 * wy1);
                feat = fmaf(wk[k], bil, feat);
            }
            b += feat;  // bev_mid

            // h = bev_mid @ W_l + b_l  (readlane broadcast of bev_mid[e'])
            float h = blv;
#pragma unroll
            for (int ep = 0; ep < ED; ++ep) {
                float be = bcast_lane(b, ep);
                h = fmaf(be, wl[ep], h);
            }
            // LayerNorm over E
            float mu = wsum64(h) * (1.0f / 64.0f);
            float d = h - mu;
            float var = wsum64(d * d) * (1.0f / 64.0f);
            float hn = d * rsqrtf(var + 1e-5f) * gv + btv;
            bev[z] = b + hn;
        }
    }

    float acc = 0.0f;
#pragma unroll
    for (int z = 0; z < ZD; ++z) acc += bev[z];
    tmp[wid * ED + lane] = acc * 0.125f;
}

// tmp (Y*X, E) -> out (E, Y*X) via LDS tile transpose
__global__ __launch_bounds__(256) void k_transpose(const float* __restrict__ tmp,
                                                   float* __restrict__ out) {
    __shared__ float tile[64][65];
    const int p0 = blockIdx.x * 64;
    const int lane = threadIdx.x & 63;
    const int r = threadIdx.x >> 6;  // 0..3
#pragma unroll
    for (int i = 0; i < 16; ++i) {
        int row = r + 4 * i;
        tile[row][lane] = tmp[(p0 + row) * ED + lane];
    }
    __syncthreads();
#pragma unroll
    for (int i = 0; i < 16; ++i) {
        int erow = r + 4 * i;
        out[erow * (YD * XD) + p0 + lane] = tile[lane][erow];
    }
}

extern "C" void kernel_launch(void* const* d_in, const int* in_sizes, int n_in,
                              void* d_out, int out_size, void* d_ws, size_t ws_size,
                              hipStream_t stream) {
    const float* Tv      = (const float*)d_in[0];   // (1,3,4)
    const float* intr    = (const float*)d_in[1];   // (1,3,3)
    const float* img     = (const float*)d_in[2];   // (1,E,FH,FW)
    const float* bev_in  = (const float*)d_in[3];   // (X,Y,Z,E)
    const float* W_off   = (const float*)d_in[4];
    const float* b_off   = (const float*)d_in[5];
    const float* s_off   = (const float*)d_in[6];
    const float* W_w     = (const float*)d_in[7];
    const float* b_w     = (const float*)d_in[8];
    const float* W_l     = (const float*)d_in[9];
    const float* b_l     = (const float*)d_in[10];
    const float* ln_g    = (const float*)d_in[11];
    const float* ln_b    = (const float*)d_in[12];
    float* out = (float*)d_out;

    float* imgHWC = (float*)d_ws;                                  // 7.86 MB
    float* tmp = (float*)((char*)d_ws + (size_t)FHD * FWD * ED * 4);  // 4 MB

    // 1) image layout transform
    {
        int n = FHD * FWD * ED;
        k_img_hwc<<<(n + 255) / 256, 256, 0, stream>>>(img, imgHWC);
    }
    // 2) main fused loop: one wave per (x,y), 8 z-points in registers
    {
        int waves = XD * YD;          // 16384
        int blocks = waves / 4;       // 4 waves per 256-thread block
        k_main<<<blocks, 256, 0, stream>>>(Tv, intr, imgHWC, bev_in,
                                           W_off, b_off, s_off, W_w, b_w,
                                           W_l, b_l, ln_g, ln_b, tmp);
    }
    // 3) transpose (Y*X,E) -> (E,Y*X)
    {
        k_transpose<<<(YD * XD) / 64, 256, 0, stream>>>(tmp, out);
    }
}

// Round 2
// 385.447 us; speedup vs baseline: 1.4116x; 1.4116x over previous
//
#include <hip/hip_runtime.h>
#include <math.h>

// Problem constants
#define XD 128
#define YD 128
#define ZD 8
#define ED 64
#define KD 3
#define NITER 3
#define FHD 96
#define FWD 320
// coord normalization uses the ORIGINAL image size (384 x 1280)
#define HALF_W 640.0f
#define HALF_H 192.0f

typedef __attribute__((ext_vector_type(8))) short short8;
typedef __attribute__((ext_vector_type(4))) float f32x4;

__device__ __forceinline__ float wsum64(float v) {
    v += __shfl_xor(v, 1, 64);
    v += __shfl_xor(v, 2, 64);
    v += __shfl_xor(v, 4, 64);
    v += __shfl_xor(v, 8, 64);
    v += __shfl_xor(v, 16, 64);
    v += __shfl_xor(v, 32, 64);
    return v;
}

// fp32 -> bf16 bits, round-to-nearest-even
__device__ __forceinline__ unsigned short f2bf(float f) {
    unsigned u = __float_as_uint(f);
    u += 0x7fff + ((u >> 16) & 1);
    return (unsigned short)(u >> 16);
}

// -------- prep 1: img (1,E,FH,FW) -> (FH*FW, E) HWC, LDS tile transpose --------
__global__ __launch_bounds__(256) void k_img_hwc(const float* __restrict__ img,
                                                 float* __restrict__ out) {
    __shared__ float tile[64][65];
    const int hw0 = blockIdx.x * 64;
    const int lane = threadIdx.x & 63;
    const int r = threadIdx.x >> 6;
#pragma unroll
    for (int i = 0; i < 16; ++i) {
        int e = r + 4 * i;
        tile[e][lane] = img[e * (FHD * FWD) + hw0 + lane];
    }
    __syncthreads();
#pragma unroll
    for (int i = 0; i < 16; ++i) {
        int row = r + 4 * i;
        out[(hw0 + row) * 64 + lane] = tile[lane][row];
    }
}

// -------- prep 2: pre-pack MFMA B-fragments (bf16) for W9 and W_l --------
// W9f:  [i][s][lane] -> short8  (3*2*64 frags)   B[k=ep][n=j] j<6:W_off j<9:W_w
// Wlf:  [i][t][s][lane] -> short8 (3*4*2*64)     B[k=ep][n=t*16+col] = W_l[i][ep][n]
__global__ void k_frags(const float* __restrict__ W_off, const float* __restrict__ W_w,
                        const float* __restrict__ W_l,
                        unsigned short* __restrict__ W9f, unsigned short* __restrict__ Wlf) {
    int idx = blockIdx.x * 256 + threadIdx.x;
    if (idx < 3 * 4 * 2 * 64) {
        int lane = idx & 63, s = (idx >> 6) & 1, t = (idx >> 7) & 3, i = idx >> 9;
        int n = t * 16 + (lane & 15), quad = lane >> 4;
#pragma unroll
        for (int jj = 0; jj < 8; ++jj) {
            int ep = s * 32 + quad * 8 + jj;
            Wlf[idx * 8 + jj] = f2bf(W_l[(i * ED + ep) * ED + n]);
        }
    } else if (idx < 3 * 4 * 2 * 64 + 3 * 2 * 64) {
        int k = idx - 3 * 4 * 2 * 64;
        int lane = k & 63, s = (k >> 6) & 1, i = k >> 7;
        int n = lane & 15, quad = lane >> 4;
#pragma unroll
        for (int jj = 0; jj < 8; ++jj) {
            int ep = s * 32 + quad * 8 + jj;
            float v = 0.0f;
            if (n < 6) v = W_off[(i * ED + ep) * 6 + n];
            else if (n < 9) v = W_w[(i * ED + ep) * 3 + (n - 6)];
            W9f[k * 8 + jj] = f2bf(v);
        }
    }
}

// -------- main fused kernel: one wave per (x,y), 8 z points, MFMA matmuls --------
__global__ __launch_bounds__(256) void k_main(
    const float* __restrict__ Tv,     // (3,4)
    const float* __restrict__ intr,   // (3,3)
    const float* __restrict__ imgHWC, // (FH*FW, E)
    const float* __restrict__ bev_in, // (X,Y,Z,E)
    const unsigned short* __restrict__ W9f,
    const unsigned short* __restrict__ Wlf,
    const float* __restrict__ b_off,  // (I,6)
    const float* __restrict__ s_off,  // (I,)
    const float* __restrict__ b_w,    // (I,3)
    const float* __restrict__ b_l,    // (I,E)
    const float* __restrict__ ln_g,   // (I,E)
    const float* __restrict__ ln_b,   // (I,E)
    float* __restrict__ tmp)          // (Y*X, E)
{
    // per-wave private LDS regions (no barriers needed)
    __shared__ unsigned short Abuf[4][16 * 64];  // A operand staging (bf16 bits)
    __shared__ float Dbuf[4][16 * 16];           // stage-1 logits
    __shared__ float Hbuf[4][16 * 65];           // stage-2 h, padded stride

    const int lane = threadIdx.x & 63;
    const int w = threadIdx.x >> 6;
    const int wid = blockIdx.x * 4 + w;
    const int x = wid & (XD - 1);
    const int y = wid >> 7;
    const int m16 = lane & 15;
    const int quad = lane >> 4;

    unsigned short* Ab = Abuf[w];
    float* Db = Dbuf[w];
    float* Hb = Hbuf[w];

    // T = intr @ Tv (3x4)
    float T[12];
#pragma unroll
    for (int r = 0; r < 3; ++r)
#pragma unroll
        for (int c = 0; c < 4; ++c)
            T[r * 4 + c] = intr[r * 3 + 0] * Tv[0 * 4 + c] +
                           intr[r * 3 + 1] * Tv[1 * 4 + c] +
                           intr[r * 3 + 2] * Tv[2 * 4 + c];

    const float gx = x * 0.8f;
    const float gy = 51.2f - y * 0.8f;

    float cx[ZD], cy[ZD];
#pragma unroll
    for (int z = 0; z < ZD; ++z) {
        float gz = z * 0.5f - 2.5f;
        float p0 = T[0] * gx + T[1] * gy + T[2] * gz + T[3];
        float p1 = T[4] * gx + T[5] * gy + T[6] * gz + T[7];
        float p2 = T[8] * gx + T[9] * gy + T[10] * gz + T[11];
        cx[z] = (p0 / p2) / HALF_W - 1.0f;
        cy[z] = (p1 / p2) / HALF_H - 1.0f;
    }

    float bev[ZD];
    const int pbase = (((x << 7) | y) << 9);
#pragma unroll
    for (int z = 0; z < ZD; ++z) bev[z] = bev_in[pbase + z * ED + lane];

    for (int i = 0; i < NITER; ++i) {
        // ============ stage 1: off/w logits via MFMA ============
#pragma unroll
        for (int z = 0; z < ZD; ++z) Ab[z * 64 + lane] = f2bf(bev[z]);

        short8 b0 = *(const short8*)(W9f + ((i * 2 + 0) * 64 + lane) * 8);
        short8 b1 = *(const short8*)(W9f + ((i * 2 + 1) * 64 + lane) * 8);
        float cbias = (m16 < 6) ? b_off[i * 6 + m16]
                                : ((m16 < 9) ? b_w[i * 3 + (m16 - 6)] : 0.0f);
        f32x4 dlog = {cbias, cbias, cbias, cbias};
        short8 a0 = *(const short8*)(Ab + m16 * 64 + quad * 8);
        short8 a1 = *(const short8*)(Ab + m16 * 64 + 32 + quad * 8);
        dlog = __builtin_amdgcn_mfma_f32_16x16x32_bf16(a0, b0, dlog, 0, 0, 0);
        dlog = __builtin_amdgcn_mfma_f32_16x16x32_bf16(a1, b1, dlog, 0, 0, 0);
#pragma unroll
        for (int r = 0; r < 4; ++r) Db[(quad * 4 + r) * 16 + m16] = dlog[r];

        const float so = s_off[i];
        float b2[ZD];
#pragma unroll
        for (int z = 0; z < ZD; ++z) {
            // broadcast-read 9 logits for this z (all lanes same addr)
            float4 q0 = *(const float4*)(Db + z * 16);      // off 0..3
            float4 q1 = *(const float4*)(Db + z * 16 + 4);  // off 4,5 + w 0,1
            float l2v = Db[z * 16 + 8];                     // w 2
            float offv[6] = {q0.x * so, q0.y * so, q0.z * so,
                             q0.w * so, q1.x * so, q1.y * so};
            float l0 = q1.z, l1 = q1.w, l2 = l2v;
            float m = fmaxf(fmaxf(l0, l1), l2);
            float e0 = __expf(l0 - m), e1 = __expf(l1 - m), e2 = __expf(l2 - m);
            float inv = 1.0f / (e0 + e1 + e2);
            float wk[3] = {e0 * inv, e1 * inv, e2 * inv};

            float feat = 0.0f;
#pragma unroll
            for (int k = 0; k < KD; ++k) {
                float gxx = cx[z] + offv[2 * k + 0];
                float gyy = cy[z] + offv[2 * k + 1];
                float px = ((gxx + 1.0f) * (float)FWD - 1.0f) * 0.5f;
                float py = ((gyy + 1.0f) * (float)FHD - 1.0f) * 0.5f;
                float x0f = floorf(px), y0f = floorf(py);
                float fx = px - x0f, fy = py - y0f;
                int ix0 = (int)x0f, iy0 = (int)y0f;
                int ix1 = ix0 + 1, iy1 = iy0 + 1;
                float mx0 = (ix0 >= 0 && ix0 < FWD) ? 1.0f : 0.0f;
                float mx1 = (ix1 >= 0 && ix1 < FWD) ? 1.0f : 0.0f;
                float my0 = (iy0 >= 0 && iy0 < FHD) ? 1.0f : 0.0f;
                float my1 = (iy1 >= 0 && iy1 < FHD) ? 1.0f : 0.0f;
                int cx0 = min(max(ix0, 0), FWD - 1);
                int cx1 = min(max(ix1, 0), FWD - 1);
                int cy0 = min(max(iy0, 0), FHD - 1);
                int cy1 = min(max(iy1, 0), FHD - 1);
                float v00 = imgHWC[(cy0 * FWD + cx0) * ED + lane] * (mx0 * my0);
                float v10 = imgHWC[(cy0 * FWD + cx1) * ED + lane] * (mx1 * my0);
                float v01 = imgHWC[(cy1 * FWD + cx0) * ED + lane] * (mx0 * my1);
                float v11 = imgHWC[(cy1 * FWD + cx1) * ED + lane] * (mx1 * my1);
                float wx1 = fx, wx0 = 1.0f - fx;
                float wy1 = fy, wy0 = 1.0f - fy;
                float bil = v00 * (wx0 * wy0) + v10 * (wx1 * wy0) +
                            v01 * (wx0 * wy1) + v11 * (wx1 * wy1);
                feat = fmaf(wk[k], bil, feat);
            }
            b2[z] = bev[z] + feat;  // bev_mid
        }

        // ============ stage 2: h = bev_mid @ W_l + b_l via MFMA ============
#pragma unroll
        for (int z = 0; z < ZD; ++z) Ab[z * 64 + lane] = f2bf(b2[z]);
        short8 a0b = *(const short8*)(Ab + m16 * 64 + quad * 8);
        short8 a1b = *(const short8*)(Ab + m16 * 64 + 32 + quad * 8);
#pragma unroll
        for (int t = 0; t < 4; ++t) {
            int n = t * 16 + m16;
            short8 w0 = *(const short8*)(Wlf + (((i * 4 + t) * 2 + 0) * 64 + lane) * 8);
            short8 w1 = *(const short8*)(Wlf + (((i * 4 + t) * 2 + 1) * 64 + lane) * 8);
            float bb = b_l[i * ED + n];
            f32x4 acc = {bb, bb, bb, bb};
            acc = __builtin_amdgcn_mfma_f32_16x16x32_bf16(a0b, w0, acc, 0, 0, 0);
            acc = __builtin_amdgcn_mfma_f32_16x16x32_bf16(a1b, w1, acc, 0, 0, 0);
#pragma unroll
            for (int r = 0; r < 4; ++r) Hb[(quad * 4 + r) * 65 + n] = acc[r];
        }

        const float gv = ln_g[i * ED + lane];
        const float btv = ln_b[i * ED + lane];
#pragma unroll
        for (int z = 0; z < ZD; ++z) {
            float h = Hb[z * 65 + lane];
            float mu = wsum64(h) * (1.0f / 64.0f);
            float d = h - mu;
            float var = wsum64(d * d) * (1.0f / 64.0f);
            float hn = d * rsqrtf(var + 1e-5f) * gv + btv;
            bev[z] = b2[z] + hn;
        }
    }

    float acc = 0.0f;
#pragma unroll
    for (int z = 0; z < ZD; ++z) acc += bev[z];
    tmp[wid * ED + lane] = acc * 0.125f;
}

// tmp (Y*X, E) -> out (E, Y*X) via LDS tile transpose
__global__ __launch_bounds__(256) void k_transpose(const float* __restrict__ tmp,
                                                   float* __restrict__ out) {
    __shared__ float tile[64][65];
    const int p0 = blockIdx.x * 64;
    const int lane = threadIdx.x & 63;
    const int r = threadIdx.x >> 6;
#pragma unroll
    for (int i = 0; i < 16; ++i) {
        int row = r + 4 * i;
        tile[row][lane] = tmp[(p0 + row) * ED + lane];
    }
    __syncthreads();
#pragma unroll
    for (int i = 0; i < 16; ++i) {
        int erow = r + 4 * i;
        out[erow * (YD * XD) + p0 + lane] = tile[lane][erow];
    }
}

extern "C" void kernel_launch(void* const* d_in, const int* in_sizes, int n_in,
                              void* d_out, int out_size, void* d_ws, size_t ws_size,
                              hipStream_t stream) {
    const float* Tv      = (const float*)d_in[0];
    const float* intr    = (const float*)d_in[1];
    const float* img     = (const float*)d_in[2];
    const float* bev_in  = (const float*)d_in[3];
    const float* W_off   = (const float*)d_in[4];
    const float* b_off   = (const float*)d_in[5];
    const float* s_off   = (const float*)d_in[6];
    const float* W_w     = (const float*)d_in[7];
    const float* b_w     = (const float*)d_in[8];
    const float* W_l     = (const float*)d_in[9];
    const float* b_l     = (const float*)d_in[10];
    const float* ln_g    = (const float*)d_in[11];
    const float* ln_b    = (const float*)d_in[12];
    float* out = (float*)d_out;

    char* ws = (char*)d_ws;
    float* imgHWC = (float*)ws;                               // 7,864,320 B
    float* tmp = (float*)(ws + 7864320);                      // 4,194,304 B
    unsigned short* W9f = (unsigned short*)(ws + 7864320 + 4194304);       // 6,144 B
    unsigned short* Wlf = (unsigned short*)(ws + 7864320 + 4194304 + 6144); // 24,576 B

    // prep kernels
    k_img_hwc<<<(FHD * FWD) / 64, 256, 0, stream>>>(img, imgHWC);
    k_frags<<<8, 256, 0, stream>>>(W_off, W_w, W_l, W9f, Wlf);

    // main fused loop
    k_main<<<(XD * YD) / 4, 256, 0, stream>>>(Tv, intr, imgHWC, bev_in,
                                              W9f, Wlf, b_off, s_off, b_w,
                                              b_l, ln_g, ln_b, tmp);
    // transpose (Y*X,E) -> (E,Y*X)
    k_transpose<<<(YD * XD) / 64, 256, 0, stream>>>(tmp, out);
}

// Round 3
// 353.388 us; speedup vs baseline: 1.5396x; 1.0907x over previous
//
#include <hip/hip_runtime.h>
#include <math.h>

// Problem constants
#define XD 128
#define YD 128
#define ZD 8
#define ED 64
#define KD 3
#define NITER 3
#define FHD 96
#define FWD 320
#define HALF_W 640.0f
#define HALF_H 192.0f

#define ASTRIDE 80   // shorts per A-tile row (160 B: 16B-aligned, banks spread)
#define HSTRIDE 68   // floats per H-tile row

typedef __attribute__((ext_vector_type(8))) short short8;
typedef __attribute__((ext_vector_type(4))) float f32x4;

__device__ __forceinline__ unsigned short f2bf(float f) {
    unsigned u = __float_as_uint(f);
    u += 0x7fff + ((u >> 16) & 1);
    return (unsigned short)(u >> 16);
}

__device__ __forceinline__ float rdlane(float v, int lane) {
    return __int_as_float(__builtin_amdgcn_readlane(__float_as_int(v), lane));
}
__device__ __forceinline__ float rdfirst_f(float v) {
    return __int_as_float(__builtin_amdgcn_readfirstlane(__float_as_int(v)));
}

// -------- prep: img CHW->HWC transpose (blocks 0..479) + weight frags (480+) ------
__global__ __launch_bounds__(256) void k_prep(const float* __restrict__ img,
                                              float* __restrict__ outHWC,
                                              const float* __restrict__ W_off,
                                              const float* __restrict__ W_w,
                                              const float* __restrict__ W_l,
                                              unsigned short* __restrict__ W9f,
                                              unsigned short* __restrict__ Wlf) {
    if (blockIdx.x < (FHD * FWD) / 64) {
        __shared__ float tile[64][65];
        const int hw0 = blockIdx.x * 64;
        const int lane = threadIdx.x & 63;
        const int r = threadIdx.x >> 6;
#pragma unroll
        for (int i = 0; i < 16; ++i) {
            int e = r + 4 * i;
            tile[e][lane] = img[e * (FHD * FWD) + hw0 + lane];
        }
        __syncthreads();
#pragma unroll
        for (int i = 0; i < 16; ++i) {
            int row = r + 4 * i;
            outHWC[(hw0 + row) * 64 + lane] = tile[lane][row];
        }
    } else {
        int idx = (blockIdx.x - (FHD * FWD) / 64) * 256 + threadIdx.x;
        if (idx < 3 * 4 * 2 * 64) {
            int lane = idx & 63, s = (idx >> 6) & 1, t = (idx >> 7) & 3, i = idx >> 9;
            int n = t * 16 + (lane & 15), quad = lane >> 4;
#pragma unroll
            for (int jj = 0; jj < 8; ++jj) {
                int ep = s * 32 + quad * 8 + jj;
                Wlf[idx * 8 + jj] = f2bf(W_l[(i * ED + ep) * ED + n]);
            }
        } else if (idx < 3 * 4 * 2 * 64 + 3 * 2 * 64) {
            int k = idx - 3 * 4 * 2 * 64;
            int lane = k & 63, s = (k >> 6) & 1, i = k >> 7;
            int n = lane & 15, quad = lane >> 4;
#pragma unroll
            for (int jj = 0; jj < 8; ++jj) {
                int ep = s * 32 + quad * 8 + jj;
                float v = 0.0f;
                if (n < 6) v = W_off[(i * ED + ep) * 6 + n];
                else if (n < 9) v = W_w[(i * ED + ep) * 3 + (n - 6)];
                W9f[k * 8 + jj] = f2bf(v);
            }
        }
    }
}

// -------- main fused kernel: one wave per TWO (x,y) points, 16 MFMA rows --------
__global__ __launch_bounds__(256) void k_main(
    const float* __restrict__ Tv,     // (3,4)
    const float* __restrict__ intr,   // (3,3)
    const float* __restrict__ imgHWC, // (FH*FW, E)
    const float* __restrict__ bev_in, // (X,Y,Z,E)
    const unsigned short* __restrict__ W9f,
    const unsigned short* __restrict__ Wlf,
    const float* __restrict__ b_off,  // (I,6)
    const float* __restrict__ s_off,  // (I,)
    const float* __restrict__ b_w,    // (I,3)
    const float* __restrict__ b_l,    // (I,E)
    const float* __restrict__ ln_g,   // (I,E)
    const float* __restrict__ ln_b,   // (I,E)
    float* __restrict__ tmp)          // (Y*X, E)
{
    __shared__ unsigned short Abuf[4][16 * ASTRIDE];
    __shared__ float Hbuf[4][16 * HSTRIDE];

    const int lane = threadIdx.x & 63;
    const int wv = threadIdx.x >> 6;
    const int wid2 = __builtin_amdgcn_readfirstlane(blockIdx.x * 4 + wv);
    const int m16 = lane & 15;
    const int quad = lane >> 4;

    unsigned short* Ab = Abuf[wv];
    float* Hb = Hbuf[wv];

    // T = intr @ Tv (3x4), uniform
    float T[12];
#pragma unroll
    for (int r = 0; r < 3; ++r)
#pragma unroll
        for (int c = 0; c < 4; ++c)
            T[r * 4 + c] = intr[r * 3 + 0] * Tv[0 * 4 + c] +
                           intr[r * 3 + 1] * Tv[1 * 4 + c] +
                           intr[r * 3 + 2] * Tv[2 * 4 + c];

    // two points per wave; 16 rows m = p*8 + z
    int cxs[16], cys[16];  // uniform coord bits in SGPRs
    float bev[16];
#pragma unroll
    for (int p = 0; p < 2; ++p) {
        int q = 2 * wid2 + p;
        int x = q & (XD - 1);
        int y = q >> 7;
        float gx = x * 0.8f;
        float gy = 51.2f - y * 0.8f;
        int pbase = (((x << 7) | y) << 9);
#pragma unroll
        for (int z = 0; z < ZD; ++z) {
            float gz = z * 0.5f - 2.5f;
            float p0 = T[0] * gx + T[1] * gy + T[2] * gz + T[3];
            float p1 = T[4] * gx + T[5] * gy + T[6] * gz + T[7];
            float p2 = T[8] * gx + T[9] * gy + T[10] * gz + T[11];
            float cxv = (p0 / p2) / HALF_W - 1.0f;
            float cyv = (p1 / p2) / HALF_H - 1.0f;
            cxs[p * 8 + z] = __builtin_amdgcn_readfirstlane(__float_as_int(cxv));
            cys[p * 8 + z] = __builtin_amdgcn_readfirstlane(__float_as_int(cyv));
            bev[p * 8 + z] = bev_in[pbase + z * ED + lane];
        }
    }

    for (int i = 0; i < NITER; ++i) {
        // ---- stage 1: logits = bev(16x64) @ W9(64x9) via 2 MFMAs ----
#pragma unroll
        for (int m = 0; m < 16; ++m) Ab[m * ASTRIDE + lane] = f2bf(bev[m]);

        short8 wb0 = *(const short8*)(W9f + ((i * 2 + 0) * 64 + lane) * 8);
        short8 wb1 = *(const short8*)(W9f + ((i * 2 + 1) * 64 + lane) * 8);
        short8 a0 = *(const short8*)(Ab + m16 * ASTRIDE + quad * 8);
        short8 a1 = *(const short8*)(Ab + m16 * ASTRIDE + 32 + quad * 8);
        f32x4 dlog = {0.0f, 0.0f, 0.0f, 0.0f};
        dlog = __builtin_amdgcn_mfma_f32_16x16x32_bf16(a0, wb0, dlog, 0, 0, 0);
        dlog = __builtin_amdgcn_mfma_f32_16x16x32_bf16(a1, wb1, dlog, 0, 0, 0);

        const float so = s_off[i];
        const float bo0 = b_off[i * 6 + 0], bo1 = b_off[i * 6 + 1], bo2 = b_off[i * 6 + 2];
        const float bo3 = b_off[i * 6 + 3], bo4 = b_off[i * 6 + 4], bo5 = b_off[i * 6 + 5];
        const float bw0 = b_w[i * 3 + 0], bw1 = b_w[i * 3 + 1], bw2 = b_w[i * 3 + 2];

        float b2[16];
#pragma unroll
        for (int m = 0; m < 16; ++m) {
            const int sl = (m >> 2) * 16;  // source lane group for row m
            const int rg = m & 3;
            // broadcast logits for this row (uniform -> SGPR)
            float lg[9];
#pragma unroll
            for (int j = 0; j < 9; ++j) lg[j] = rdlane(dlog[rg], sl + j);
            float offv[6] = {(lg[0] + bo0) * so, (lg[1] + bo1) * so, (lg[2] + bo2) * so,
                             (lg[3] + bo3) * so, (lg[4] + bo4) * so, (lg[5] + bo5) * so};
            float l0 = lg[6] + bw0, l1 = lg[7] + bw1, l2 = lg[8] + bw2;
            float mx = fmaxf(fmaxf(l0, l1), l2);
            float e0 = __expf(l0 - mx), e1 = __expf(l1 - mx), e2 = __expf(l2 - mx);
            float inv = 1.0f / (e0 + e1 + e2);
            float wk0 = e0 * inv, wk1 = e1 * inv, wk2 = e2 * inv;
            float wks[3] = {wk0, wk1, wk2};

            const float cxf = __int_as_float(cxs[m]);
            const float cyf = __int_as_float(cys[m]);
            float feat = 0.0f;
#pragma unroll
            for (int k = 0; k < KD; ++k) {
                float gxx = cxf + offv[2 * k + 0];
                float gyy = cyf + offv[2 * k + 1];
                float px = ((gxx + 1.0f) * (float)FWD - 1.0f) * 0.5f;
                float py = ((gyy + 1.0f) * (float)FHD - 1.0f) * 0.5f;
                float x0f = floorf(px), y0f = floorf(py);
                float fx = px - x0f, fy = py - y0f;
                int ix0 = __builtin_amdgcn_readfirstlane((int)x0f);
                int iy0 = __builtin_amdgcn_readfirstlane((int)y0f);
                int ix1 = ix0 + 1, iy1 = iy0 + 1;
                float mx0 = (ix0 >= 0 && ix0 < FWD) ? 1.0f : 0.0f;
                float mx1 = (ix1 >= 0 && ix1 < FWD) ? 1.0f : 0.0f;
                float my0 = (iy0 >= 0 && iy0 < FHD) ? 1.0f : 0.0f;
                float my1 = (iy1 >= 0 && iy1 < FHD) ? 1.0f : 0.0f;
                int cx0 = min(max(ix0, 0), FWD - 1);
                int cx1 = min(max(ix1, 0), FWD - 1);
                int cy0 = min(max(iy0, 0), FHD - 1);
                int cy1 = min(max(iy1, 0), FHD - 1);
                int r0 = cy0 * FWD, r1 = cy1 * FWD;  // scalar
                float v00 = imgHWC[((r0 + cx0) << 6) + lane] * (mx0 * my0);
                float v10 = imgHWC[((r0 + cx1) << 6) + lane] * (mx1 * my0);
                float v01 = imgHWC[((r1 + cx0) << 6) + lane] * (mx0 * my1);
                float v11 = imgHWC[((r1 + cx1) << 6) + lane] * (mx1 * my1);
                float wx1 = fx, wx0 = 1.0f - fx;
                float wy1 = fy, wy0 = 1.0f - fy;
                float bil = v00 * (wx0 * wy0) + v10 * (wx1 * wy0) +
                            v01 * (wx0 * wy1) + v11 * (wx1 * wy1);
                feat = fmaf(wks[k], bil, feat);
            }
            b2[m] = bev[m] + feat;  // bev_mid
        }

        // ---- stage 2: h = bev_mid(16x64) @ W_l + b_l via 8 MFMAs ----
#pragma unroll
        for (int m = 0; m < 16; ++m) Ab[m * ASTRIDE + lane] = f2bf(b2[m]);
        short8 a0b = *(const short8*)(Ab + m16 * ASTRIDE + quad * 8);
        short8 a1b = *(const short8*)(Ab + m16 * ASTRIDE + 32 + quad * 8);
        f32x4 accs[4];
#pragma unroll
        for (int t = 0; t < 4; ++t) {
            float bb = b_l[i * ED + t * 16 + m16];
            f32x4 acc = {bb, bb, bb, bb};
            short8 w0 = *(const short8*)(Wlf + (((i * 4 + t) * 2 + 0) * 64 + lane) * 8);
            short8 w1 = *(const short8*)(Wlf + (((i * 4 + t) * 2 + 1) * 64 + lane) * 8);
            acc = __builtin_amdgcn_mfma_f32_16x16x32_bf16(a0b, w0, acc, 0, 0, 0);
            acc = __builtin_amdgcn_mfma_f32_16x16x32_bf16(a1b, w1, acc, 0, 0, 0);
            accs[t] = acc;
        }

        // ---- LayerNorm in D-layout: rows quad*4+r, cols t*16+m16 ----
        float s1[4], s2[4];
#pragma unroll
        for (int r = 0; r < 4; ++r) {
            s1[r] = accs[0][r] + accs[1][r] + accs[2][r] + accs[3][r];
            s2[r] = accs[0][r] * accs[0][r];
            s2[r] = fmaf(accs[1][r], accs[1][r], s2[r]);
            s2[r] = fmaf(accs[2][r], accs[2][r], s2[r]);
            s2[r] = fmaf(accs[3][r], accs[3][r], s2[r]);
        }
#pragma unroll
        for (int d = 1; d <= 8; d <<= 1) {
#pragma unroll
            for (int r = 0; r < 4; ++r) {
                s1[r] += __shfl_xor(s1[r], d, 64);
                s2[r] += __shfl_xor(s2[r], d, 64);
            }
        }
        float gt[4], bt[4];
#pragma unroll
        for (int t = 0; t < 4; ++t) {
            gt[t] = ln_g[i * ED + t * 16 + m16];
            bt[t] = ln_b[i * ED + t * 16 + m16];
        }
#pragma unroll
        for (int r = 0; r < 4; ++r) {
            float mu = s1[r] * (1.0f / 64.0f);
            float var = fmaxf(s2[r] * (1.0f / 64.0f) - mu * mu, 0.0f);
            float rs = rsqrtf(var + 1e-5f);
            int row = quad * 4 + r;
#pragma unroll
            for (int t = 0; t < 4; ++t) {
                float hn = (accs[t][r] - mu) * rs * gt[t] + bt[t];
                Hb[row * HSTRIDE + t * 16 + m16] = hn;
            }
        }
        // residual back in lane=channel layout
#pragma unroll
        for (int m = 0; m < 16; ++m) bev[m] = b2[m] + Hb[m * HSTRIDE + lane];
    }

    // z-mean, write two tmp rows
#pragma unroll
    for (int p = 0; p < 2; ++p) {
        float s = 0.0f;
#pragma unroll
        for (int z = 0; z < ZD; ++z) s += bev[p * 8 + z];
        tmp[(2 * wid2 + p) * ED + lane] = s * 0.125f;
    }
}

// tmp (Y*X, E) -> out (E, Y*X) via LDS tile transpose
__global__ __launch_bounds__(256) void k_transpose(const float* __restrict__ tmp,
                                                   float* __restrict__ out) {
    __shared__ float tile[64][65];
    const int p0 = blockIdx.x * 64;
    const int lane = threadIdx.x & 63;
    const int r = threadIdx.x >> 6;
#pragma unroll
    for (int i = 0; i < 16; ++i) {
        int row = r + 4 * i;
        tile[row][lane] = tmp[(p0 + row) * ED + lane];
    }
    __syncthreads();
#pragma unroll
    for (int i = 0; i < 16; ++i) {
        int erow = r + 4 * i;
        out[erow * (YD * XD) + p0 + lane] = tile[lane][erow];
    }
}

extern "C" void kernel_launch(void* const* d_in, const int* in_sizes, int n_in,
                              void* d_out, int out_size, void* d_ws, size_t ws_size,
                              hipStream_t stream) {
    const float* Tv      = (const float*)d_in[0];
    const float* intr    = (const float*)d_in[1];
    const float* img     = (const float*)d_in[2];
    const float* bev_in  = (const float*)d_in[3];
    const float* W_off   = (const float*)d_in[4];
    const float* b_off   = (const float*)d_in[5];
    const float* s_off   = (const float*)d_in[6];
    const float* W_w     = (const float*)d_in[7];
    const float* b_w     = (const float*)d_in[8];
    const float* W_l     = (const float*)d_in[9];
    const float* b_l     = (const float*)d_in[10];
    const float* ln_g    = (const float*)d_in[11];
    const float* ln_b    = (const float*)d_in[12];
    float* out = (float*)d_out;

    char* ws = (char*)d_ws;
    float* imgHWC = (float*)ws;                                            // 7,864,320 B
    float* tmp = (float*)(ws + 7864320);                                   // 4,194,304 B
    unsigned short* W9f = (unsigned short*)(ws + 7864320 + 4194304);       // 6,144 B
    unsigned short* Wlf = (unsigned short*)(ws + 7864320 + 4194304 + 6144);// 24,576 B

    // prep: img transpose (480 blocks) + weight frags (8 blocks)
    k_prep<<<(FHD * FWD) / 64 + 8, 256, 0, stream>>>(img, imgHWC, W_off, W_w, W_l,
                                                     W9f, Wlf);
    // main fused loop: 8192 waves, 2 points each
    k_main<<<(XD * YD / 2) / 4, 256, 0, stream>>>(Tv, intr, imgHWC, bev_in,
                                                  W9f, Wlf, b_off, s_off, b_w,
                                                  b_l, ln_g, ln_b, tmp);
    // transpose (Y*X,E) -> (E,Y*X)
    k_transpose<<<(YD * XD) / 64, 256, 0, stream>>>(tmp, out);
}

// Round 4
// 181.459 us; speedup vs baseline: 2.9984x; 1.9475x over previous
//
#include <hip/hip_runtime.h>
#include <math.h>

// Problem constants
#define XD 128
#define YD 128
#define ZD 8
#define ED 64
#define KD 3
#define NITER 3
#define FHD 96
#define FWD 320
#define HALF_W 640.0f
#define HALF_H 192.0f

#define ASTRIDE 80   // shorts per A-tile row (160 B, 16B-aligned, banks spread)
#define DSTR 28      // floats per logit-tile row (112 B, 16B-aligned)
#define HSTRIDE 68   // floats per H-tile row

// per-wave LDS region offsets (bytes)
#define OFF_AB   0       // 16*80*2 = 2560
#define OFF_SD   2560    // 48 int4  = 768
#define OFF_SW   3328    // 48 float4 = 768
#define OFF_DH   4096    // max(16*28*4, 16*68*4) = 4352  (Db / Hb union)
#define OFF_CXY  8448    // 32 floats = 128
#define WAVE_LDS 8576

typedef __attribute__((ext_vector_type(8))) short short8;
typedef __attribute__((ext_vector_type(4))) float f32x4;

__device__ __forceinline__ unsigned short f2bf(float f) {
    unsigned u = __float_as_uint(f);
    u += 0x7fff + ((u >> 16) & 1);
    return (unsigned short)(u >> 16);
}

// -------- prep: img CHW->HWC transpose (blocks 0..479) + weight frags (480+) ------
__global__ __launch_bounds__(256) void k_prep(const float* __restrict__ img,
                                              float* __restrict__ outHWC,
                                              const float* __restrict__ W_off,
                                              const float* __restrict__ W_w,
                                              const float* __restrict__ W_l,
                                              unsigned short* __restrict__ W9f,
                                              unsigned short* __restrict__ Wlf) {
    if (blockIdx.x < (FHD * FWD) / 64) {
        __shared__ float tile[64][65];
        const int hw0 = blockIdx.x * 64;
        const int lane = threadIdx.x & 63;
        const int r = threadIdx.x >> 6;
#pragma unroll
        for (int i = 0; i < 16; ++i) {
            int e = r + 4 * i;
            tile[e][lane] = img[e * (FHD * FWD) + hw0 + lane];
        }
        __syncthreads();
#pragma unroll
        for (int i = 0; i < 16; ++i) {
            int row = r + 4 * i;
            outHWC[(hw0 + row) * 64 + lane] = tile[lane][row];
        }
    } else {
        int idx = (blockIdx.x - (FHD * FWD) / 64) * 256 + threadIdx.x;
        if (idx < 3 * 4 * 2 * 64) {
            int lane = idx & 63, s = (idx >> 6) & 1, t = (idx >> 7) & 3, i = idx >> 9;
            int n = t * 16 + (lane & 15), quad = lane >> 4;
#pragma unroll
            for (int jj = 0; jj < 8; ++jj) {
                int ep = s * 32 + quad * 8 + jj;
                Wlf[idx * 8 + jj] = f2bf(W_l[(i * ED + ep) * ED + n]);
            }
        } else if (idx < 3 * 4 * 2 * 64 + 3 * 2 * 64) {
            int k = idx - 3 * 4 * 2 * 64;
            int lane = k & 63, s = (k >> 6) & 1, i = k >> 7;
            int n = lane & 15, quad = lane >> 4;
#pragma unroll
            for (int jj = 0; jj < 8; ++jj) {
                int ep = s * 32 + quad * 8 + jj;
                float v = 0.0f;
                if (n < 6) v = W_off[(i * ED + ep) * 6 + n];
                else if (n < 9) v = W_w[(i * ED + ep) * 3 + (n - 6)];
                W9f[k * 8 + jj] = f2bf(v);
            }
        }
    }
}

// -------- main fused kernel: one wave per TWO (x,y) points, 16 MFMA rows --------
__global__ __launch_bounds__(256, 4) void k_main(
    const float* __restrict__ Tv,     // (3,4)
    const float* __restrict__ intr,   // (3,3)
    const float* __restrict__ imgHWC, // (FH*FW, E)
    const float* __restrict__ bev_in, // (X,Y,Z,E)
    const unsigned short* __restrict__ W9f,
    const unsigned short* __restrict__ Wlf,
    const float* __restrict__ b_off,  // (I,6)
    const float* __restrict__ s_off,  // (I,)
    const float* __restrict__ b_w,    // (I,3)
    const float* __restrict__ b_l,    // (I,E)
    const float* __restrict__ ln_g,   // (I,E)
    const float* __restrict__ ln_b,   // (I,E)
    float* __restrict__ tmp)          // (Y*X, E)
{
    __shared__ __align__(16) char smem[4][WAVE_LDS];

    const int lane = threadIdx.x & 63;
    const int wv = threadIdx.x >> 6;
    const int wid2 = __builtin_amdgcn_readfirstlane(blockIdx.x * 4 + wv);
    const int m16 = lane & 15;
    const int quad = lane >> 4;

    char* base = smem[wv];
    unsigned short* Ab = (unsigned short*)(base + OFF_AB);
    int*   Sd  = (int*)(base + OFF_SD);
    float* Sw  = (float*)(base + OFF_SW);
    float* Db  = (float*)(base + OFF_DH);
    float* Hb  = (float*)(base + OFF_DH);   // union with Db (disjoint lifetimes)
    float* Cxy = (float*)(base + OFF_CXY);

    // T = intr @ Tv (3x4), uniform
    float T[12];
#pragma unroll
    for (int r = 0; r < 3; ++r)
#pragma unroll
        for (int c = 0; c < 4; ++c)
            T[r * 4 + c] = intr[r * 3 + 0] * Tv[0 * 4 + c] +
                           intr[r * 3 + 1] * Tv[1 * 4 + c] +
                           intr[r * 3 + 2] * Tv[2 * 4 + c];

    // two points per wave; rows m = p*8 + z; cx/cy stashed in LDS
    float bev[16];
#pragma unroll
    for (int p = 0; p < 2; ++p) {
        int q = 2 * wid2 + p;
        int x = q & (XD - 1);
        int y = q >> 7;
        float gx = x * 0.8f;
        float gy = 51.2f - y * 0.8f;
        int pbase = (((x << 7) | y) << 9);
#pragma unroll
        for (int z = 0; z < ZD; ++z) {
            float gz = z * 0.5f - 2.5f;
            float p0 = T[0] * gx + T[1] * gy + T[2] * gz + T[3];
            float p1 = T[4] * gx + T[5] * gy + T[6] * gz + T[7];
            float p2 = T[8] * gx + T[9] * gy + T[10] * gz + T[11];
            float cxv = (p0 / p2) / HALF_W - 1.0f;
            float cyv = (p1 / p2) / HALF_H - 1.0f;
            int m = p * 8 + z;
            if (lane == 0) {
                Cxy[m * 2 + 0] = cxv;
                Cxy[m * 2 + 1] = cyv;
            }
            bev[m] = bev_in[pbase + z * ED + lane];
        }
    }

    for (int i = 0; i < NITER; ++i) {
        // ---- stage 1: logits = bev(16x64) @ W9(64x9) via 2 MFMAs ----
#pragma unroll
        for (int m = 0; m < 16; ++m) Ab[m * ASTRIDE + lane] = f2bf(bev[m]);

        short8 wb0 = *(const short8*)(W9f + ((i * 2 + 0) * 64 + lane) * 8);
        short8 wb1 = *(const short8*)(W9f + ((i * 2 + 1) * 64 + lane) * 8);
        short8 a0 = *(const short8*)(Ab + m16 * ASTRIDE + quad * 8);
        short8 a1 = *(const short8*)(Ab + m16 * ASTRIDE + 32 + quad * 8);
        f32x4 dlog = {0.0f, 0.0f, 0.0f, 0.0f};
        dlog = __builtin_amdgcn_mfma_f32_16x16x32_bf16(a0, wb0, dlog, 0, 0, 0);
        dlog = __builtin_amdgcn_mfma_f32_16x16x32_bf16(a1, wb1, dlog, 0, 0, 0);
        // D-layout: row quad*4+r, col m16
#pragma unroll
        for (int r = 0; r < 4; ++r) Db[(quad * 4 + r) * DSTR + m16] = dlog[r];

        const float so = s_off[i];
        const float bo0 = b_off[i * 6 + 0], bo1 = b_off[i * 6 + 1], bo2 = b_off[i * 6 + 2];
        const float bo3 = b_off[i * 6 + 3], bo4 = b_off[i * 6 + 4], bo5 = b_off[i * 6 + 5];
        const float bw0 = b_w[i * 3 + 0], bw1 = b_w[i * 3 + 1], bw2 = b_w[i * 3 + 2];

        // ---- phase B: lane-parallel sample descriptors (48 lanes = 16 rows x 3 k) --
        if (lane < 48) {
            int m = lane / 3;
            int k = lane - m * 3;
            const float* Dm = Db + m * DSTR;
            float4 qa = *(const float4*)(Dm);       // logits 0..3
            float4 qb = *(const float4*)(Dm + 4);   // logits 4..7
            float l8 = Dm[8];

            float ox0 = (qa.x + bo0) * so, oy0 = (qa.y + bo1) * so;
            float ox1 = (qa.z + bo2) * so, oy1 = (qa.w + bo3) * so;
            float ox2 = (qb.x + bo4) * so, oy2 = (qb.y + bo5) * so;
            float l0 = qb.z + bw0, l1 = qb.w + bw1, l2 = l8 + bw2;
            float mx = fmaxf(fmaxf(l0, l1), l2);
            float e0 = __expf(l0 - mx), e1 = __expf(l1 - mx), e2 = __expf(l2 - mx);
            float inv = 1.0f / (e0 + e1 + e2);
            float wk0 = e0 * inv, wk1 = e1 * inv, wk2 = e2 * inv;

            float wkk = (k == 0) ? wk0 : ((k == 1) ? wk1 : wk2);
            float ox  = (k == 0) ? ox0 : ((k == 1) ? ox1 : ox2);
            float oy  = (k == 0) ? oy0 : ((k == 1) ? oy1 : oy2);

            float2 c = *(const float2*)(Cxy + m * 2);
            float gxx = c.x + ox, gyy = c.y + oy;
            float px = ((gxx + 1.0f) * (float)FWD - 1.0f) * 0.5f;
            float py = ((gyy + 1.0f) * (float)FHD - 1.0f) * 0.5f;
            float x0f = floorf(px), y0f = floorf(py);
            float fx = px - x0f, fy = py - y0f;
            int ix0 = (int)x0f, iy0 = (int)y0f;
            int ix1 = ix0 + 1, iy1 = iy0 + 1;
            float mx0 = (ix0 >= 0 && ix0 < FWD) ? 1.0f : 0.0f;
            float mx1 = (ix1 >= 0 && ix1 < FWD) ? 1.0f : 0.0f;
            float my0 = (iy0 >= 0 && iy0 < FHD) ? 1.0f : 0.0f;
            float my1 = (iy1 >= 0 && iy1 < FHD) ? 1.0f : 0.0f;
            int cx0 = min(max(ix0, 0), FWD - 1);
            int cx1 = min(max(ix1, 0), FWD - 1);
            int cy0 = min(max(iy0, 0), FHD - 1);
            int cy1 = min(max(iy1, 0), FHD - 1);
            int r0 = cy0 * FWD, r1 = cy1 * FWD;
            float wx1 = fx, wx0 = 1.0f - fx;
            float wy1 = fy, wy0 = 1.0f - fy;
            *(int4*)(Sd + lane * 4) =
                make_int4(r0 + cx0, r0 + cx1, r1 + cx0, r1 + cx1);
            *(float4*)(Sw + lane * 4) =
                make_float4(wkk * wx0 * wy0 * mx0 * my0, wkk * wx1 * wy0 * mx1 * my0,
                            wkk * wx0 * wy1 * mx0 * my1, wkk * wx1 * wy1 * mx1 * my1);
        }

        // ---- sampling: 48 samples, broadcast descriptors, 4 coalesced loads each --
        float b2[16];
#pragma unroll
        for (int m = 0; m < 16; ++m) {
            float feat = 0.0f;
#pragma unroll
            for (int k = 0; k < KD; ++k) {
                int s = m * 3 + k;
                int4 id = *(const int4*)(Sd + s * 4);
                float4 w4 = *(const float4*)(Sw + s * 4);
                feat = fmaf(w4.x, imgHWC[(id.x << 6) + lane], feat);
                feat = fmaf(w4.y, imgHWC[(id.y << 6) + lane], feat);
                feat = fmaf(w4.z, imgHWC[(id.z << 6) + lane], feat);
                feat = fmaf(w4.w, imgHWC[(id.w << 6) + lane], feat);
            }
            b2[m] = bev[m] + feat;  // bev_mid
        }

        // ---- stage 2: h = bev_mid(16x64) @ W_l + b_l via 8 MFMAs ----
#pragma unroll
        for (int m = 0; m < 16; ++m) Ab[m * ASTRIDE + lane] = f2bf(b2[m]);
        short8 a0b = *(const short8*)(Ab + m16 * ASTRIDE + quad * 8);
        short8 a1b = *(const short8*)(Ab + m16 * ASTRIDE + 32 + quad * 8);
        f32x4 accs[4];
#pragma unroll
        for (int t = 0; t < 4; ++t) {
            float bb = b_l[i * ED + t * 16 + m16];
            f32x4 acc = {bb, bb, bb, bb};
            short8 w0 = *(const short8*)(Wlf + (((i * 4 + t) * 2 + 0) * 64 + lane) * 8);
            short8 w1 = *(const short8*)(Wlf + (((i * 4 + t) * 2 + 1) * 64 + lane) * 8);
            acc = __builtin_amdgcn_mfma_f32_16x16x32_bf16(a0b, w0, acc, 0, 0, 0);
            acc = __builtin_amdgcn_mfma_f32_16x16x32_bf16(a1b, w1, acc, 0, 0, 0);
            accs[t] = acc;
        }

        // ---- LayerNorm in D-layout: rows quad*4+r, cols t*16+m16 ----
        float s1[4], s2[4];
#pragma unroll
        for (int r = 0; r < 4; ++r) {
            s1[r] = accs[0][r] + accs[1][r] + accs[2][r] + accs[3][r];
            s2[r] = accs[0][r] * accs[0][r];
            s2[r] = fmaf(accs[1][r], accs[1][r], s2[r]);
            s2[r] = fmaf(accs[2][r], accs[2][r], s2[r]);
            s2[r] = fmaf(accs[3][r], accs[3][r], s2[r]);
        }
#pragma unroll
        for (int d = 1; d <= 8; d <<= 1) {
#pragma unroll
            for (int r = 0; r < 4; ++r) {
                s1[r] += __shfl_xor(s1[r], d, 64);
                s2[r] += __shfl_xor(s2[r], d, 64);
            }
        }
        float gt[4], bt[4];
#pragma unroll
        for (int t = 0; t < 4; ++t) {
            gt[t] = ln_g[i * ED + t * 16 + m16];
            bt[t] = ln_b[i * ED + t * 16 + m16];
        }
#pragma unroll
        for (int r = 0; r < 4; ++r) {
            float mu = s1[r] * (1.0f / 64.0f);
            float var = fmaxf(s2[r] * (1.0f / 64.0f) - mu * mu, 0.0f);
            float rs = rsqrtf(var + 1e-5f);
            int row = quad * 4 + r;
#pragma unroll
            for (int t = 0; t < 4; ++t) {
                float hn = (accs[t][r] - mu) * rs * gt[t] + bt[t];
                Hb[row * HSTRIDE + t * 16 + m16] = hn;
            }
        }
        // residual back in lane=channel layout
#pragma unroll
        for (int m = 0; m < 16; ++m) bev[m] = b2[m] + Hb[m * HSTRIDE + lane];
    }

    // z-mean, write two tmp rows
#pragma unroll
    for (int p = 0; p < 2; ++p) {
        float s = 0.0f;
#pragma unroll
        for (int z = 0; z < ZD; ++z) s += bev[p * 8 + z];
        tmp[(2 * wid2 + p) * ED + lane] = s * 0.125f;
    }
}

// tmp (Y*X, E) -> out (E, Y*X) via LDS tile transpose
__global__ __launch_bounds__(256) void k_transpose(const float* __restrict__ tmp,
                                                   float* __restrict__ out) {
    __shared__ float tile[64][65];
    const int p0 = blockIdx.x * 64;
    const int lane = threadIdx.x & 63;
    const int r = threadIdx.x >> 6;
#pragma unroll
    for (int i = 0; i < 16; ++i) {
        int row = r + 4 * i;
        tile[row][lane] = tmp[(p0 + row) * ED + lane];
    }
    __syncthreads();
#pragma unroll
    for (int i = 0; i < 16; ++i) {
        int erow = r + 4 * i;
        out[erow * (YD * XD) + p0 + lane] = tile[lane][erow];
    }
}

extern "C" void kernel_launch(void* const* d_in, const int* in_sizes, int n_in,
                              void* d_out, int out_size, void* d_ws, size_t ws_size,
                              hipStream_t stream) {
    const float* Tv      = (const float*)d_in[0];
    const float* intr    = (const float*)d_in[1];
    const float* img     = (const float*)d_in[2];
    const float* bev_in  = (const float*)d_in[3];
    const float* W_off   = (const float*)d_in[4];
    const float* b_off   = (const float*)d_in[5];
    const float* s_off   = (const float*)d_in[6];
    const float* W_w     = (const float*)d_in[7];
    const float* b_w     = (const float*)d_in[8];
    const float* W_l     = (const float*)d_in[9];
    const float* b_l     = (const float*)d_in[10];
    const float* ln_g    = (const float*)d_in[11];
    const float* ln_b    = (const float*)d_in[12];
    float* out = (float*)d_out;

    char* ws = (char*)d_ws;
    float* imgHWC = (float*)ws;                                            // 7,864,320 B
    float* tmp = (float*)(ws + 7864320);                                   // 4,194,304 B
    unsigned short* W9f = (unsigned short*)(ws + 7864320 + 4194304);       // 6,144 B
    unsigned short* Wlf = (unsigned short*)(ws + 7864320 + 4194304 + 6144);// 24,576 B

    // prep: img transpose (480 blocks) + weight frags (8 blocks)
    k_prep<<<(FHD * FWD) / 64 + 8, 256, 0, stream>>>(img, imgHWC, W_off, W_w, W_l,
                                                     W9f, Wlf);
    // main fused loop: 8192 waves, 2 points each
    k_main<<<(XD * YD / 2) / 4, 256, 0, stream>>>(Tv, intr, imgHWC, bev_in,
                                                  W9f, Wlf, b_off, s_off, b_w,
                                                  b_l, ln_g, ln_b, tmp);
    // transpose (Y*X,E) -> (E,Y*X)
    k_transpose<<<(YD * XD) / 64, 256, 0, stream>>>(tmp, out);
}